// Round 5
// baseline (76.058 us; speedup 1.0000x reference)
//
#include <hip/hip_runtime.h>
#include <hip/hip_bf16.h>

typedef float f32x4 __attribute__((ext_vector_type(4)));
typedef __bf16 bf16x8 __attribute__((ext_vector_type(8)));

constexpr int B2     = 512;
constexpr int KDIM   = 65536;      // 256*16*16
constexpr int TM     = 128;        // tile size (4x4 grid, keep i<=j: 10 tiles)
constexpr int BK     = 32;
constexpr int NK     = KDIM / BK;  // 2048
constexpr int NTILE  = 10;
constexpr int KSPLIT = 76;
constexpr int NBLK   = NTILE * KSPLIT;  // 760 = 8*95 -> ~3 blocks/CU

// thread t: row r = t>>1, k-half h = t&1 -> 4 consecutive float4 from that row
__device__ __forceinline__ void issue_panel(float4* p, const float* __restrict__ src,
                                            int k0, int tid) {
    const float* g = src + (size_t)(tid >> 1) * KDIM + k0 + (tid & 1) * 16;
#pragma unroll
    for (int it = 0; it < 4; ++it)
        p[it] = *reinterpret_cast<const float4*>(g + it * 4);
}

// cvt fp32->bf16, write 2x b128 into XOR-swizzled [128][32] bf16 panel.
// logical 16B-slot q of row r lives at physical slot q ^ (r&3).
__device__ __forceinline__ void write_panel(__bf16* panel, const float4* p, int tid) {
    int r = tid >> 1, h = tid & 1;
    bf16x8 v0, v1;
    v0[0] = (__bf16)p[0].x; v0[1] = (__bf16)p[0].y; v0[2] = (__bf16)p[0].z; v0[3] = (__bf16)p[0].w;
    v0[4] = (__bf16)p[1].x; v0[5] = (__bf16)p[1].y; v0[6] = (__bf16)p[1].z; v0[7] = (__bf16)p[1].w;
    v1[0] = (__bf16)p[2].x; v1[1] = (__bf16)p[2].y; v1[2] = (__bf16)p[2].z; v1[3] = (__bf16)p[2].w;
    v1[4] = (__bf16)p[3].x; v1[5] = (__bf16)p[3].y; v1[6] = (__bf16)p[3].z; v1[7] = (__bf16)p[3].w;
    char* base = reinterpret_cast<char*>(panel) + r * 64;
    *reinterpret_cast<bf16x8*>(base + (((2 * h)     ^ (r & 3)) * 16)) = v0;
    *reinterpret_cast<bf16x8*>(base + (((2 * h + 1) ^ (r & 3)) * 16)) = v1;
}

// barrier that does NOT drain vmcnt: ds-ops visible (lgkmcnt 0), register
// global-loads stay in flight across it.
__device__ __forceinline__ void lds_barrier() {
    asm volatile("s_waitcnt lgkmcnt(0)" ::: "memory");
    __builtin_amdgcn_s_barrier();
}

__global__ __launch_bounds__(256, 3) void gemm_partial(const float* __restrict__ X,
                                                       __bf16* __restrict__ partials) {
    __shared__ __align__(16) __bf16 lds[2][2][TM * BK];   // [dbuf][panel] 8KB each = 32KB

    // bijective chunked XCD swizzle (760 = 8*95): consecutive L share an XCD
    int d = blockIdx.x;
    int L = (d & 7) * 95 + (d >> 3);
    int split = L / NTILE;
    int t     = L - split * NTILE;          // split-major: one split's 10 tiles adjacent
    int i = (t >= 9) ? 3 : (t >= 7) ? 2 : (t >= 4) ? 1 : 0;
    int j = t - ((i == 0) ? 0 : (i == 1) ? 3 : (i == 2) ? 5 : 6);
    bool diag = (i == j);
    const float* Abase = X + (size_t)i * TM * KDIM;
    const float* Bbase = X + (size_t)j * TM * KDIM;

    int tid  = threadIdx.x;
    int lane = tid & 63;
    int wave = tid >> 6;         // 4 waves: 2(M) x 2(N), each owns 64x64
    int wr = wave >> 1, wc = wave & 1;

    int s0 = split * NK / KSPLIT;
    int s1 = (split + 1) * NK / KSPLIT;

    f32x4 acc[4][4] = {};
    float4 pa[4], pb[4];

    // per-lane LDS read bases: row = base + (lane&15); physical slot (lane>>4)^(lane&3)
    int pslot  = ((lane >> 4) ^ (lane & 3)) * 16;
    int rbyteA = (wr * 64 + (lane & 15)) * 64 + pslot;
    int rbyteB = (wc * 64 + (lane & 15)) * 64 + pslot;

    // prologue: stage s0 -> buf0; issue s0+1 loads (fly across barrier)
    issue_panel(pa, Abase, s0 * BK, tid);
    if (!diag) issue_panel(pb, Bbase, s0 * BK, tid);
    write_panel(&lds[0][0][0], pa, tid);
    if (!diag) write_panel(&lds[0][1][0], pb, tid);
    if (s0 + 1 < s1) {
        issue_panel(pa, Abase, (s0 + 1) * BK, tid);
        if (!diag) issue_panel(pb, Bbase, (s0 + 1) * BK, tid);
    }
    lds_barrier();

    for (int s = s0; s < s1; ++s) {
        int cur = (s - s0) & 1;
        const char* bA = (const char*)&lds[cur][0][0];
        const char* bB = diag ? bA : (const char*)&lds[cur][1][0];

        bf16x8 bfr[4];
#pragma unroll
        for (int ni = 0; ni < 4; ++ni)
            bfr[ni] = *reinterpret_cast<const bf16x8*>(bB + rbyteB + ni * 1024);
#pragma unroll
        for (int mi = 0; mi < 4; ++mi) {
            bf16x8 a = *reinterpret_cast<const bf16x8*>(bA + rbyteA + mi * 1024);
#pragma unroll
            for (int ni = 0; ni < 4; ++ni)
                acc[mi][ni] = __builtin_amdgcn_mfma_f32_16x16x32_bf16(
                    a, bfr[ni], acc[mi][ni], 0, 0, 0);
        }

        if (s + 1 < s1) {
            // write-late (compiler inserts vmcnt wait at first pa use), then
            // immediately re-issue next loads so they fly across the barrier
            write_panel(&lds[cur ^ 1][0][0], pa, tid);
            if (!diag) write_panel(&lds[cur ^ 1][1][0], pb, tid);
            if (s + 2 < s1) {
                issue_panel(pa, Abase, (s + 2) * BK, tid);
                if (!diag) issue_panel(pb, Bbase, (s + 2) * BK, tid);
            }
        }
        lds_barrier();
    }

    // epilogue: 128x128 bf16 partial
    __bf16* out = partials + (size_t)(t * KSPLIT + split) * (TM * TM);
    int col = lane & 15, rquad = (lane >> 4) * 4;
#pragma unroll
    for (int mi = 0; mi < 4; ++mi)
#pragma unroll
        for (int ni = 0; ni < 4; ++ni) {
            int cj = wc * 64 + ni * 16 + col;
#pragma unroll
            for (int v = 0; v < 4; ++v) {
                int ri = wr * 64 + mi * 16 + rquad + v;
                out[ri * TM + cj] = (__bf16)acc[mi][ni][v];
            }
        }
}

__global__ __launch_bounds__(256) void reduce_partials(const __bf16* __restrict__ partials,
                                                       float* __restrict__ C) {
    int idx = blockIdx.x * 256 + threadIdx.x;   // 10 tiles * 4096 float4-groups
    int t   = idx / 4096;
    int e4  = idx & 4095;
    int r   = e4 >> 5;          // row 0..127
    int c4  = e4 & 31;          // float4-col 0..31
    const __bf16* src = partials + (size_t)t * KSPLIT * (TM * TM) + r * TM + c4 * 4;
    float sx = 0.f, sy = 0.f, sz = 0.f, sw = 0.f;
    for (int s = 0; s < KSPLIT; ++s) {
        ushort4 v = *reinterpret_cast<const ushort4*>(src + (size_t)s * (TM * TM));
        union { unsigned u; float f; } a, b, c2, d2;
        a.u  = (unsigned)v.x << 16;  b.u  = (unsigned)v.y << 16;
        c2.u = (unsigned)v.z << 16;  d2.u = (unsigned)v.w << 16;
        sx += a.f; sy += b.f; sz += c2.f; sw += d2.f;
    }
    int i = (t >= 9) ? 3 : (t >= 7) ? 2 : (t >= 4) ? 1 : 0;
    int j = t - ((i == 0) ? 0 : (i == 1) ? 3 : (i == 2) ? 5 : 6);
    int gi = i * TM + r;
    int gj = j * TM + c4 * 4;
    float4 sum = make_float4(sx, sy, sz, sw);
    *reinterpret_cast<float4*>(C + gi * 512 + gj) = sum;
    if (i != j) {
        C[(gj + 0) * 512 + gi] = sum.x;
        C[(gj + 1) * 512 + gi] = sum.y;
        C[(gj + 2) * 512 + gi] = sum.z;
        C[(gj + 3) * 512 + gi] = sum.w;
    }
}

// loss = mean( clip(sq_i + sq_j - 2*C_ij, 1e-12) * mask(i,j)^2 )
__global__ __launch_bounds__(256) void loss_kernel(const float* __restrict__ C,
                                                   const int* __restrict__ ranking,
                                                   const int* __restrict__ choice,
                                                   const int* __restrict__ ncp,
                                                   float* __restrict__ out) {
    __shared__ int pos[16];
    __shared__ float wsum[4];
    int i   = blockIdx.x;
    int tid = threadIdx.x;
    if (tid < 16) pos[ranking[i * 16 + tid]] = tid;
    __syncthreads();

    float nc  = (float)(*ncp);
    int   ci  = choice[i];
    float c   = (float)ci;
    float sqi = C[i * 513];
    float sum = 0.f;

    for (int j = tid; j < B2; j += 256) {
        int   lbl = ranking[j * 16];
        int   r   = pos[lbl];
        float sqj = C[j * 513];
        float d2  = sqi + sqj - 2.f * C[i * 512 + j];
        d2 = fmaxf(d2, 1e-12f);
        float jf = (float)r;
        float m  = (r < ci) ? (1.f - jf / c) : (-(jf - c + 1.f) / (nc - c));
        sum += d2 * m * m;
    }

    for (int off = 32; off > 0; off >>= 1) sum += __shfl_down(sum, off);
    int lane = tid & 63, wave = tid >> 6;
    if (lane == 0) wsum[wave] = sum;
    __syncthreads();
    if (tid == 0) {
        float tsum = wsum[0] + wsum[1] + wsum[2] + wsum[3];
        atomicAdd(out, tsum * (1.f / ((float)B2 * (float)B2)));
    }
}

extern "C" void kernel_launch(void* const* d_in, const int* in_sizes, int n_in,
                              void* d_out, int out_size, void* d_ws, size_t ws_size,
                              hipStream_t stream) {
    const float* X       = (const float*)d_in[0];
    const int*   ranking = (const int*)d_in[1];
    const int*   choice  = (const int*)d_in[2];
    const int*   ncp     = (const int*)d_in[3];
    float*       ws      = (float*)d_ws;

    // ws layout: C (512*512 f32 = 1 MB) | partials (760 * 16384 bf16 = 24.9 MB)
    float*  C        = ws;
    __bf16* partials = (__bf16*)(ws + 262144);

    hipMemsetAsync(d_out, 0, sizeof(float), stream);

    gemm_partial<<<dim3(NBLK), dim3(256), 0, stream>>>(X, partials);
    reduce_partials<<<dim3(NTILE * 4096 / 256), dim3(256), 0, stream>>>(partials, C);
    loss_kernel<<<dim3(B2), dim3(256), 0, stream>>>(C, ranking, choice, ncp, (float*)d_out);
}

// Round 6
// 69.143 us; speedup vs baseline: 1.1000x; 1.1000x over previous
//
#include <hip/hip_runtime.h>
#include <hip/hip_bf16.h>

typedef float f32x4 __attribute__((ext_vector_type(4)));
typedef __bf16 bf16x8 __attribute__((ext_vector_type(8)));

constexpr int B2     = 512;
constexpr int KDIM   = 65536;     // 256*16*16
constexpr int BM     = 256;
constexpr int BK     = 32;
constexpr int NK     = KDIM / BK; // 2048 K-steps
constexpr int KSPLIT = 85;
constexpr int NBLK   = 3 * KSPLIT; // 255

// async 16B global->LDS; LDS dest = wave-uniform base + lane*16
__device__ __forceinline__ void gload16(const void* g, void* l) {
    __builtin_amdgcn_global_load_lds(
        (__attribute__((address_space(1))) void*)(g),
        (__attribute__((address_space(3))) void*)(l), 16, 0, 0);
}

// one quarter (64 rows) of a 256x32 fp32 panel, linear LDS dest,
// XOR-swizzled SOURCE: LDS slot (r,s) holds global 16B slot (s ^ (r&7)).
__device__ __forceinline__ void stage_q(const float* __restrict__ src, int k0,
                                        float* ldsPanel, int tid, int it) {
    int r    = it * 64 + (tid >> 3);
    int slot = (tid & 7) ^ (r & 7);
    gload16(src + (size_t)r * KDIM + k0 + slot * 4,
            (char*)ldsPanel + it * 8192 + (tid & ~63) * 16);
}

// read 8 consecutive fp32 (k-slice) from swizzled fp32 tile, convert to bf16x8
__device__ __forceinline__ bf16x8 read_frag(const char* base, int rowByte, int s0b, int s1b) {
    f32x4 lo = *reinterpret_cast<const f32x4*>(base + rowByte + s0b);
    f32x4 hi = *reinterpret_cast<const f32x4*>(base + rowByte + s1b);
    bf16x8 r;
    r[0] = (__bf16)lo[0]; r[1] = (__bf16)lo[1]; r[2] = (__bf16)lo[2]; r[3] = (__bf16)lo[3];
    r[4] = (__bf16)hi[0]; r[5] = (__bf16)hi[1]; r[6] = (__bf16)hi[2]; r[7] = (__bf16)hi[3];
    return r;
}

__global__ __launch_bounds__(512, 2) void gemm_partial(const float* __restrict__ X,
                                                       __bf16* __restrict__ partials) {
    __shared__ __align__(16) float ldsT[2][2][BM * BK];   // [dbuf][panel] = 128 KB

    // bijective chunked XCD swizzle, split-major (one split's 3 tiles share an XCD L2)
    int d = blockIdx.x;
    int xcd = d & 7, slotb = d >> 3;
    int L = (xcd < 7 ? xcd * 32 : 224) + slotb;
    int split = L / 3;
    int tile  = L - split * 3;            // 0:(0,0) 1:(0,1) 2:(1,1)

    int ti = (tile == 2) ? 1 : 0;
    int tj = (tile == 0) ? 0 : 1;
    bool diag = (ti == tj);
    const float* Abase = X + (size_t)ti * 256 * KDIM;
    const float* Bbase = X + (size_t)tj * 256 * KDIM;

    int tid  = threadIdx.x;
    int lane = tid & 63;
    int wave = tid >> 6;       // 8 waves: 2(M) x 4(N)
    int wr = wave >> 2, wc = wave & 3;

    int s0 = split * NK / KSPLIT;
    int s1 = (split + 1) * NK / KSPLIT;

    f32x4 acc[8][4] = {};

    // lane's two swizzled 16B-slot byte offsets (row&7 == lane&7 for all frag rows)
    int q  = lane >> 4;
    int rx = lane & 7;
    int s0b = ((2 * q)     ^ rx) * 16;
    int s1b = ((2 * q + 1) ^ rx) * 16;
    int rA0 = (wr * 128 + (lane & 15)) * 128;   // A frag mi at rA0 + mi*2048
    int rB0 = (wc * 64  + (lane & 15)) * 128;   // B frag ni at rB0 + ni*2048

    // prologue: stage tile s0 fully into buf 0
#pragma unroll
    for (int it = 0; it < 4; ++it) {
        stage_q(Abase, s0 * BK, &ldsT[0][0][0], tid, it);
        if (!diag) stage_q(Bbase, s0 * BK, &ldsT[0][1][0], tid, it);
    }

    for (int s = s0; s < s1; ++s) {
        int cur = (s - s0) & 1;
        const char* bA = (const char*)&ldsT[cur][0][0];
        const char* bB = diag ? bA : (const char*)&ldsT[cur][1][0];
        float* nA = &ldsT[cur ^ 1][0][0];
        float* nB = &ldsT[cur ^ 1][1][0];
        bool pre = (s + 1 < s1);
        int nk0 = (s + 1) * BK;

        // step-top: tile s resident (own loads issued >=1 phase ago; drain ~empty)
        asm volatile("s_waitcnt vmcnt(0)" ::: "memory");
        __builtin_amdgcn_s_barrier();

        // ---- phase 0: B frags (held all step) + A0,A1; stage quarters 0,1 ----
        bf16x8 bfr[4];
#pragma unroll
        for (int ni = 0; ni < 4; ++ni)
            bfr[ni] = read_frag(bB, rB0 + ni * 2048, s0b, s1b);
        bf16x8 a0 = read_frag(bA, rA0 + 0 * 2048, s0b, s1b);
        bf16x8 a1 = read_frag(bA, rA0 + 1 * 2048, s0b, s1b);
        if (pre) {
            stage_q(Abase, nk0, nA, tid, 0);
            if (!diag) stage_q(Bbase, nk0, nB, tid, 0);
            stage_q(Abase, nk0, nA, tid, 1);
            if (!diag) stage_q(Bbase, nk0, nB, tid, 1);
        }
        asm volatile("s_waitcnt lgkmcnt(0)" ::: "memory");
        __builtin_amdgcn_s_setprio(1);
#pragma unroll
        for (int ni = 0; ni < 4; ++ni)
            acc[0][ni] = __builtin_amdgcn_mfma_f32_16x16x32_bf16(a0, bfr[ni], acc[0][ni], 0, 0, 0);
#pragma unroll
        for (int ni = 0; ni < 4; ++ni)
            acc[1][ni] = __builtin_amdgcn_mfma_f32_16x16x32_bf16(a1, bfr[ni], acc[1][ni], 0, 0, 0);
        __builtin_amdgcn_s_setprio(0);
        a0 = read_frag(bA, rA0 + 2 * 2048, s0b, s1b);   // next phase's frags before barrier
        a1 = read_frag(bA, rA0 + 3 * 2048, s0b, s1b);
        __builtin_amdgcn_s_barrier();

        // ---- phase 1: MFMA mi=2,3; stage quarter 2 ----
        if (pre) {
            stage_q(Abase, nk0, nA, tid, 2);
            if (!diag) stage_q(Bbase, nk0, nB, tid, 2);
        }
        asm volatile("s_waitcnt lgkmcnt(0)" ::: "memory");
        __builtin_amdgcn_s_setprio(1);
#pragma unroll
        for (int ni = 0; ni < 4; ++ni)
            acc[2][ni] = __builtin_amdgcn_mfma_f32_16x16x32_bf16(a0, bfr[ni], acc[2][ni], 0, 0, 0);
#pragma unroll
        for (int ni = 0; ni < 4; ++ni)
            acc[3][ni] = __builtin_amdgcn_mfma_f32_16x16x32_bf16(a1, bfr[ni], acc[3][ni], 0, 0, 0);
        __builtin_amdgcn_s_setprio(0);
        a0 = read_frag(bA, rA0 + 4 * 2048, s0b, s1b);
        a1 = read_frag(bA, rA0 + 5 * 2048, s0b, s1b);
        __builtin_amdgcn_s_barrier();

        // ---- phase 2: MFMA mi=4,5; stage quarter 3 ----
        if (pre) {
            stage_q(Abase, nk0, nA, tid, 3);
            if (!diag) stage_q(Bbase, nk0, nB, tid, 3);
        }
        asm volatile("s_waitcnt lgkmcnt(0)" ::: "memory");
        __builtin_amdgcn_s_setprio(1);
#pragma unroll
        for (int ni = 0; ni < 4; ++ni)
            acc[4][ni] = __builtin_amdgcn_mfma_f32_16x16x32_bf16(a0, bfr[ni], acc[4][ni], 0, 0, 0);
#pragma unroll
        for (int ni = 0; ni < 4; ++ni)
            acc[5][ni] = __builtin_amdgcn_mfma_f32_16x16x32_bf16(a1, bfr[ni], acc[5][ni], 0, 0, 0);
        __builtin_amdgcn_s_setprio(0);
        a0 = read_frag(bA, rA0 + 6 * 2048, s0b, s1b);
        a1 = read_frag(bA, rA0 + 7 * 2048, s0b, s1b);
        __builtin_amdgcn_s_barrier();

        // ---- phase 3: MFMA mi=6,7 (reads fully drained before next step-top barrier) ----
        asm volatile("s_waitcnt lgkmcnt(0)" ::: "memory");
        __builtin_amdgcn_s_setprio(1);
#pragma unroll
        for (int ni = 0; ni < 4; ++ni)
            acc[6][ni] = __builtin_amdgcn_mfma_f32_16x16x32_bf16(a0, bfr[ni], acc[6][ni], 0, 0, 0);
#pragma unroll
        for (int ni = 0; ni < 4; ++ni)
            acc[7][ni] = __builtin_amdgcn_mfma_f32_16x16x32_bf16(a1, bfr[ni], acc[7][ni], 0, 0, 0);
        __builtin_amdgcn_s_setprio(0);
    }

    // epilogue: bf16 partial tile
    __bf16* out = partials + (size_t)(tile * KSPLIT + split) * (BM * BM);
    int col = lane & 15, rquad = (lane >> 4) * 4;
#pragma unroll
    for (int mi = 0; mi < 8; ++mi)
#pragma unroll
        for (int ni = 0; ni < 4; ++ni) {
            int j = wc * 64 + ni * 16 + col;
#pragma unroll
            for (int v = 0; v < 4; ++v) {
                int i = wr * 128 + mi * 16 + rquad + v;
                out[i * BM + j] = (__bf16)acc[mi][ni][v];
            }
        }
}

__global__ __launch_bounds__(256) void reduce_partials(const __bf16* __restrict__ partials,
                                                       float* __restrict__ C) {
    int idx  = blockIdx.x * 256 + threadIdx.x;   // over 3*16384 groups of 4
    int tile = idx / 16384;
    int e4   = idx & 16383;
    const __bf16* p = partials + (size_t)tile * KSPLIT * 65536 + e4 * 4;
    float sx = 0.f, sy = 0.f, sz = 0.f, sw = 0.f;
    for (int s = 0; s < KSPLIT; ++s) {
        ushort4 v = *reinterpret_cast<const ushort4*>(p + (size_t)s * 65536);
        union { unsigned u; float f; } a, b, c2, d2;
        a.u  = (unsigned)v.x << 16;  b.u  = (unsigned)v.y << 16;
        c2.u = (unsigned)v.z << 16;  d2.u = (unsigned)v.w << 16;
        sx += a.f; sy += b.f; sz += c2.f; sw += d2.f;
    }
    int e = e4 * 4;
    int i = e >> 8, j = e & 255;
    int gi = (tile == 2) ? 256 + i : i;
    int gj = (tile == 0) ? j : 256 + j;
    float4 sum = make_float4(sx, sy, sz, sw);
    *reinterpret_cast<float4*>(C + gi * 512 + gj) = sum;
    if (tile == 1) {
        C[(gj + 0) * 512 + gi] = sum.x;
        C[(gj + 1) * 512 + gi] = sum.y;
        C[(gj + 2) * 512 + gi] = sum.z;
        C[(gj + 3) * 512 + gi] = sum.w;
    }
}

// loss = mean( clip(sq_i + sq_j - 2*C_ij, 1e-12) * mask(i,j)^2 )
__global__ __launch_bounds__(256) void loss_kernel(const float* __restrict__ C,
                                                   const int* __restrict__ ranking,
                                                   const int* __restrict__ choice,
                                                   const int* __restrict__ ncp,
                                                   float* __restrict__ out) {
    __shared__ int pos[16];
    __shared__ float wsum[4];
    int i   = blockIdx.x;
    int tid = threadIdx.x;
    if (tid < 16) pos[ranking[i * 16 + tid]] = tid;
    __syncthreads();

    float nc  = (float)(*ncp);
    int   ci  = choice[i];
    float c   = (float)ci;
    float sqi = C[i * 513];
    float sum = 0.f;

    for (int j = tid; j < B2; j += 256) {
        int   lbl = ranking[j * 16];
        int   r   = pos[lbl];
        float sqj = C[j * 513];
        float d2  = sqi + sqj - 2.f * C[i * 512 + j];
        d2 = fmaxf(d2, 1e-12f);
        float jf = (float)r;
        float m  = (r < ci) ? (1.f - jf / c) : (-(jf - c + 1.f) / (nc - c));
        sum += d2 * m * m;
    }

    for (int off = 32; off > 0; off >>= 1) sum += __shfl_down(sum, off);
    int lane = tid & 63, wave = tid >> 6;
    if (lane == 0) wsum[wave] = sum;
    __syncthreads();
    if (tid == 0) {
        float t = wsum[0] + wsum[1] + wsum[2] + wsum[3];
        atomicAdd(out, t * (1.f / ((float)B2 * (float)B2)));
    }
}

extern "C" void kernel_launch(void* const* d_in, const int* in_sizes, int n_in,
                              void* d_out, int out_size, void* d_ws, size_t ws_size,
                              hipStream_t stream) {
    const float* X       = (const float*)d_in[0];
    const int*   ranking = (const int*)d_in[1];
    const int*   choice  = (const int*)d_in[2];
    const int*   ncp     = (const int*)d_in[3];
    float*       ws      = (float*)d_ws;

    // ws layout: C (512*512 f32 = 1 MB) | partials (255 * 64K bf16 = 33.4 MB)
    float*  C        = ws;
    __bf16* partials = (__bf16*)(ws + 262144);

    hipMemsetAsync(d_out, 0, sizeof(float), stream);

    gemm_partial<<<dim3(NBLK), dim3(512), 0, stream>>>(X, partials);
    reduce_partials<<<dim3(3 * 16384 / 256), dim3(256), 0, stream>>>(partials, C);
    loss_kernel<<<dim3(B2), dim3(256), 0, stream>>>(C, ranking, choice, ncp, (float*)d_out);
}